// Round 1
// baseline (312.245 us; speedup 1.0000x reference)
//
#include <hip/hip_runtime.h>
#include <stdint.h>

typedef unsigned long long ull;

#define NA 8400
#define NB 32
#define KTOP 300
#define NC 80
#define PADK 512
#define CH 33   // 256*33 = 8448 >= 8400

// ---------------- Kernel 1: per-anchor score key ----------------
// key = monotonic-uint transform of nms_score (score>=0.2) else transform(-inf)=0x007FFFFF
__global__ __launch_bounds__(256) void score_kernel(const float* __restrict__ pred,
                                                    uint32_t* __restrict__ keys) {
    __shared__ float sP[128 * 85];
    const int blk = blockIdx.x;                       // 2100 blocks * 128 anchors = 268800
    const float4* g4 = (const float4*)(pred + (size_t)blk * 128 * 85); // 43520 B, 16B aligned
    float4* l4 = (float4*)sP;
    for (int i = threadIdx.x; i < (128 * 85 / 4); i += 256) l4[i] = g4[i];
    __syncthreads();
    const int t = threadIdx.x;
    if (t < 128) {
        const float* p = sP + t * 85;
        float obj = p[4];
        float best = p[5];
        #pragma unroll
        for (int c = 1; c < NC; ++c) { float v = p[5 + c]; if (v > best) best = v; }
        float sc = obj * best;
        uint32_t u = (sc >= 0.2f) ? (__float_as_uint(sc) | 0x80000000u) : 0x007FFFFFu;
        keys[(size_t)blk * 128 + t] = u;
    }
}

// ---------------- Kernel 2: per-batch top-k + NMS + outputs ----------------
__global__ __launch_bounds__(256) void nms_kernel(const float* __restrict__ pred,
                                                  const float* __restrict__ zone,
                                                  const uint32_t* __restrict__ keys,
                                                  float* __restrict__ out) {
    #pragma clang fp contract(off)
    __shared__ uint32_t sKeys[8448];
    __shared__ ull      sSel[PADK];
    __shared__ uint32_t sHist[256];
    __shared__ uint32_t sCnts[256];
    __shared__ float sB0[304], sB1[304], sB2[304], sB3[304];
    __shared__ float sObj[304], sConf[304];
    __shared__ int   sCls[304];
    __shared__ int   sKeep[304];
    __shared__ ull   sMask[KTOP * 5];   // suppression bitmask rows
    __shared__ ull   sKeepW[5];
    __shared__ float sZone[16];
    __shared__ uint32_t sBc[2];
    __shared__ int sCnt;

    const int b = blockIdx.x;
    const int t = threadIdx.x;

    for (int e = t; e < NA; e += 256) sKeys[e] = keys[(size_t)b * NA + e];
    for (int e = NA + t; e < 8448; e += 256) sKeys[e] = 0u;
    if (t < 16) sZone[t] = zone[t];
    if (t == 0) sCnt = 0;
    __syncthreads();

    // ---- radix select: exact 300th-largest key, rank among equals ----
    uint32_t prefix = 0, r = KTOP;
    for (int round = 0; round < 4; ++round) {
        const int shift = 24 - 8 * round;
        sHist[t] = 0u;
        __syncthreads();
        const uint32_t pmask = (round == 0) ? 0u : (0xFFFFFFFFu << (shift + 8));
        int beg = t * CH, end = beg + CH; if (end > NA) end = NA;
        for (int e = beg; e < end; ++e) {
            uint32_t k = sKeys[e];
            if ((k & pmask) == (prefix & pmask))
                atomicAdd(&sHist[(k >> shift) & 0xFFu], 1u);
        }
        __syncthreads();
        if (t == 0) {
            uint32_t cum = 0; int v;
            for (v = 255; v >= 0; --v) {
                uint32_t c = sHist[v];
                if (cum + c >= r) break;
                cum += c;
            }
            sBc[0] = prefix | ((uint32_t)v << shift);
            sBc[1] = r - cum;
        }
        __syncthreads();
        prefix = sBc[0]; r = sBc[1];
        __syncthreads();
    }
    const uint32_t kth = prefix;
    const uint32_t rem = r;              // how many ==kth to take (lowest indices)
    const uint32_t cntgt = KTOP - rem;   // count of keys strictly greater

    // ---- compact top-300 (set-exact; order fixed by the sort below) ----
    {
        int beg = t * CH, end = beg + CH; if (end > NA) end = NA;
        uint32_t eqc = 0;
        for (int e = beg; e < end; ++e) {
            uint32_t k = sKeys[e];
            if (k > kth) {
                int p = atomicAdd(&sCnt, 1);
                sSel[p] = ((ull)k << 32) | (ull)(0xFFFFFFFFu - (uint32_t)e);
            } else if (k == kth) eqc++;
        }
        sCnts[t] = eqc;
        __syncthreads();
        if (t == 0) {
            uint32_t base = 0;
            for (int i = 0; i < 256; ++i) { uint32_t c = sCnts[i]; sCnts[i] = base; base += c; }
        }
        __syncthreads();
        uint32_t off = sCnts[t];
        for (int e = beg; e < end; ++e) {
            uint32_t k = sKeys[e];
            if (k == kth) {
                if (off < rem)
                    sSel[cntgt + off] = ((ull)k << 32) | (ull)(0xFFFFFFFFu - (uint32_t)e);
                off++;
            }
        }
        for (int p = KTOP + t; p < PADK; p += 256) sSel[p] = 0ull;
        __syncthreads();
    }

    // ---- bitonic sort, descending (key desc, idx asc via ~idx) ----
    for (int kk = 2; kk <= PADK; kk <<= 1) {
        for (int j = kk >> 1; j > 0; j >>= 1) {
            __syncthreads();
            #pragma unroll
            for (int half = 0; half < 2; ++half) {
                int i = t + half * 256;
                int ixj = i ^ j;
                if (ixj > i) {
                    ull a = sSel[i], c = sSel[ixj];
                    bool desc = ((i & kk) == 0);
                    bool sw = desc ? (a < c) : (a > c);
                    if (sw) { sSel[i] = c; sSel[ixj] = a; }
                }
            }
        }
    }
    __syncthreads();

    // ---- extract + gather detection data ----
    for (int i = t; i < KTOP; i += 256) {
        ull s = sSel[i];
        uint32_t k32 = (uint32_t)(s >> 32);
        uint32_t a = 0xFFFFFFFFu - (uint32_t)(s & 0xFFFFFFFFull);
        sKeep[i] = (k32 > 0x007FFFFFu) ? 1 : 0;
        const float* p = pred + ((size_t)b * NA + a) * 85;
        float x = p[0], y = p[1], w = p[2], h = p[3], obj = p[4];
        float best = p[5]; int bc = 0;
        for (int c = 1; c < NC; ++c) { float v = p[5 + c]; if (v > best) { best = v; bc = c; } }
        float hw = w * 0.5f, hh = h * 0.5f;
        sB0[i] = x - hw; sB1[i] = y - hh; sB2[i] = x + hw; sB3[i] = y + hh;
        sObj[i] = obj; sConf[i] = best; sCls[i] = bc;
    }
    __syncthreads();

    // ---- precompute suppression bitmasks: mask[i] bit j set iff j>i && iou>0.45 ----
    for (int item = t; item < KTOP * 5; item += 256) {
        int i = item / 5, w = item % 5;
        float x1 = sB0[i], y1 = sB1[i], x2 = sB2[i], y2 = sB3[i];
        float ai = fmaxf(x2 - x1, 0.0f) * fmaxf(y2 - y1, 0.0f);
        ull bits = 0ull;
        int j0 = w * 64;
        int jmax = j0 + 64; if (jmax > KTOP) jmax = KTOP;
        int jbeg = (j0 > i + 1) ? j0 : (i + 1);
        for (int j = jbeg; j < jmax; ++j) {
            float bx1 = sB0[j], by1 = sB1[j], bx2 = sB2[j], by2 = sB3[j];
            float aj = fmaxf(bx2 - bx1, 0.0f) * fmaxf(by2 - by1, 0.0f);
            float iw = fminf(x2, bx2) - fmaxf(x1, bx1); iw = fmaxf(iw, 0.0f);
            float ih = fminf(y2, by2) - fmaxf(y1, by1); ih = fmaxf(ih, 0.0f);
            float inter = iw * ih;
            float den = ai + aj;      // mirror reference op order exactly
            den = den - inter;
            den = den + 1e-9f;
            float iou = inter / den;
            if (iou > 0.45f) bits |= (1ull << (j - j0));
        }
        sMask[item] = bits;
    }
    __syncthreads();

    // ---- sequential greedy NMS over bitmask words (single thread, 300 iters) ----
    if (t == 0) {
        ull kws[5] = {0ull, 0ull, 0ull, 0ull, 0ull};
        for (int i = 0; i < KTOP; ++i)
            if (sKeep[i]) kws[i >> 6] |= (1ull << (i & 63));
        for (int i = 0; i < KTOP; ++i) {
            if ((kws[i >> 6] >> (i & 63)) & 1ull) {
                const ull* m = &sMask[i * 5];
                kws[0] &= ~m[0]; kws[1] &= ~m[1]; kws[2] &= ~m[2];
                kws[3] &= ~m[3]; kws[4] &= ~m[4];
            }
        }
        sKeepW[0] = kws[0]; sKeepW[1] = kws[1]; sKeepW[2] = kws[2];
        sKeepW[3] = kws[3]; sKeepW[4] = kws[4];
    }
    __syncthreads();

    // ---- outputs (all float32, concatenated in return order) ----
    // boxes_yxyx (32,300,4) @0 ; in_zone @38400 ; scores @48000 ; classes @57600 ;
    // centers_yx (32,300,2) @67200 ; keep @86400 ; total 96000
    const size_t o1 = 38400, o2 = 48000, o3 = 57600, o4 = 67200, o5 = 86400;
    const size_t bo = (size_t)b * KTOP;
    for (int i = t; i < KTOP; i += 256) {
        int kp = (int)((sKeepW[i >> 6] >> (i & 63)) & 1ull);
        float x1 = sB0[i], y1 = sB1[i], x2 = sB2[i], y2 = sB3[i];
        out[(bo + i) * 4 + 0] = y1;
        out[(bo + i) * 4 + 1] = x1;
        out[(bo + i) * 4 + 2] = y2;
        out[(bo + i) * 4 + 3] = x2;
        float cx = (x1 + x2) * 0.5f;
        float cy = (y1 + y2) * 0.5f;
        int cnt = 0;
        #pragma unroll
        for (int e = 0; e < 8; ++e) {
            float xi = sZone[2 * e], yi = sZone[2 * e + 1];
            int ep = (e + 7) & 7;               // zr = roll(zone, 1): partner is zone[e-1]
            float xj = sZone[2 * ep], yj = sZone[2 * ep + 1];
            bool gyi = yi > cy, gyj = yj > cy;
            if (gyi != gyj) {
                float gx = (xj - xi) * (cy - yi) / (yj - yi) + xi;
                if (gx > cx) cnt++;
            }
        }
        int inz = (((cnt & 1) != 0) && kp) ? 1 : 0;
        out[o1 + bo + i] = (float)inz;
        out[o2 + bo + i] = fmaxf(sObj[i], sConf[i]);
        out[o3 + bo + i] = (float)sCls[i];
        out[o4 + (bo + i) * 2 + 0] = cy;
        out[o4 + (bo + i) * 2 + 1] = cx;
        out[o5 + bo + i] = (float)kp;
    }
}

extern "C" void kernel_launch(void* const* d_in, const int* in_sizes, int n_in,
                              void* d_out, int out_size, void* d_ws, size_t ws_size,
                              hipStream_t stream) {
    const float* pred = (const float*)d_in[0];   // (32,8400,85) fp32
    const float* zone = (const float*)d_in[1];   // (8,2) fp32
    float* out = (float*)d_out;                  // 96000 fp32
    uint32_t* keys = (uint32_t*)d_ws;            // 268800 * 4 B scratch

    score_kernel<<<(NB * NA) / 128, 256, 0, stream>>>(pred, keys);
    nms_kernel<<<NB, 256, 0, stream>>>(pred, zone, keys, out);
}

// Round 2
// 244.058 us; speedup vs baseline: 1.2794x; 1.2794x over previous
//
#include <hip/hip_runtime.h>
#include <stdint.h>

typedef unsigned long long ull;

#define NA 8400
#define NB 32
#define KTOP 300
#define NC 80
#define PADK 512
#define CH 33   // 256*33 = 8448 >= 8400

// ---------------- Kernel 1: per-anchor score key ----------------
// key = monotonic-uint transform of nms_score (score>=0.2) else transform(-inf)=0x007FFFFF
__global__ __launch_bounds__(256) void score_kernel(const float* __restrict__ pred,
                                                    uint32_t* __restrict__ keys) {
    __shared__ float sP[128 * 85];
    const int blk = blockIdx.x;                       // 2100 blocks * 128 anchors = 268800
    const float4* g4 = (const float4*)(pred + (size_t)blk * 128 * 85); // 43520 B, 16B aligned
    float4* l4 = (float4*)sP;
    for (int i = threadIdx.x; i < (128 * 85 / 4); i += 256) l4[i] = g4[i];
    __syncthreads();
    const int t = threadIdx.x;
    if (t < 128) {
        const float* p = sP + t * 85;
        float obj = p[4];
        float best = p[5];
        #pragma unroll
        for (int c = 1; c < NC; ++c) { float v = p[5 + c]; if (v > best) best = v; }
        float sc = obj * best;
        uint32_t u = (sc >= 0.2f) ? (__float_as_uint(sc) | 0x80000000u) : 0x007FFFFFu;
        keys[(size_t)blk * 128 + t] = u;
    }
}

// ---------------- Kernel 2: per-batch top-k + NMS + outputs ----------------
__global__ __launch_bounds__(256) void nms_kernel(const float* __restrict__ pred,
                                                  const float* __restrict__ zone,
                                                  const uint32_t* __restrict__ keys,
                                                  float* __restrict__ out) {
    #pragma clang fp contract(off)
    __shared__ uint32_t sKeys[8448];
    __shared__ ull      sSel[PADK];
    __shared__ uint32_t sScanA[256];
    __shared__ uint32_t sScanB[256];
    __shared__ float sB0[304], sB1[304], sB2[304], sB3[304];
    __shared__ float sObj[304], sConf[304];
    __shared__ int   sCls[304];
    __shared__ ull   sMask[KTOP * 5];   // suppression bitmask rows (aliased as sub-hists early)
    __shared__ ull   sKeepW[5];
    __shared__ float sZone[16];
    __shared__ uint32_t sBc[2];
    __shared__ int sCnt;

    uint32_t* sH4 = (uint32_t*)sMask;   // 4 x 256 sub-histograms, radix phase only

    const int b = blockIdx.x;
    const int t = threadIdx.x;
    const int wv = t >> 6;

    for (int e = t; e < NA; e += 256) sKeys[e] = keys[(size_t)b * NA + e];
    for (int e = NA + t; e < 8448; e += 256) sKeys[e] = 0u;
    if (t < 16) sZone[t] = zone[t];
    if (t == 0) sCnt = 0;
    __syncthreads();

    // ---- radix select: exact 300th-largest key (parallel scan boundary) ----
    uint32_t prefix = 0, r = KTOP;
    const int beg = t * CH;
    const int end = (beg + CH < NA) ? beg + CH : NA;
    for (int round = 0; round < 4; ++round) {
        const int shift = 24 - 8 * round;
        for (int idx = t; idx < 1024; idx += 256) sH4[idx] = 0u;
        __syncthreads();
        const uint32_t pmask = (round == 0) ? 0u : (0xFFFFFFFFu << (shift + 8));
        for (int e = beg; e < end; ++e) {
            uint32_t k = sKeys[e];
            if ((k & pmask) == (prefix & pmask))
                atomicAdd(&sH4[(wv << 8) + ((k >> shift) & 0xFFu)], 1u);
        }
        __syncthreads();
        // merge sub-hists + inclusive SUFFIX scan (Hillis-Steele, ping-pong)
        sScanA[t] = sH4[t] + sH4[256 + t] + sH4[512 + t] + sH4[768 + t];
        __syncthreads();
        uint32_t* src = sScanA;
        uint32_t* dst = sScanB;
        for (int off = 1; off < 256; off <<= 1) {
            uint32_t v = src[t];
            if (t + off < 256) v += src[t + off];
            dst[t] = v;
            __syncthreads();
            uint32_t* tmp = src; src = dst; dst = tmp;
        }
        uint32_t S = src[t];                         // count of keys with byte >= t
        uint32_t above = (t < 255) ? src[t + 1] : 0; // count of keys with byte > t
        if (above < r && S >= r) {
            sBc[0] = prefix | ((uint32_t)t << shift);
            sBc[1] = r - above;
        }
        __syncthreads();
        prefix = sBc[0]; r = sBc[1];
        __syncthreads();
    }
    const uint32_t kth = prefix;
    const uint32_t rem = r;              // how many ==kth to take (lowest indices)
    const uint32_t cntgt = KTOP - rem;   // count of keys strictly greater

    // ---- compact top-300 (set-exact; order fixed by the sort below) ----
    {
        uint32_t eqc = 0;
        for (int e = beg; e < end; ++e) {
            uint32_t k = sKeys[e];
            if (k > kth) {
                int p = atomicAdd(&sCnt, 1);
                sSel[p] = ((ull)k << 32) | (ull)(0xFFFFFFFFu - (uint32_t)e);
            } else if (k == kth) eqc++;
        }
        sScanA[t] = eqc;
        __syncthreads();
        // inclusive PREFIX scan
        uint32_t* src = sScanA;
        uint32_t* dst = sScanB;
        for (int off = 1; off < 256; off <<= 1) {
            uint32_t v = src[t];
            if (t >= off) v += src[t - off];
            dst[t] = v;
            __syncthreads();
            uint32_t* tmp = src; src = dst; dst = tmp;
        }
        uint32_t off0 = (t > 0) ? src[t - 1] : 0;   // exclusive prefix of eq-counts
        for (int e = beg; e < end; ++e) {
            uint32_t k = sKeys[e];
            if (k == kth) {
                if (off0 < rem)
                    sSel[cntgt + off0] = ((ull)k << 32) | (ull)(0xFFFFFFFFu - (uint32_t)e);
                off0++;
            }
        }
        for (int p = KTOP + t; p < PADK; p += 256) sSel[p] = 0ull;
        __syncthreads();
    }

    // ---- bitonic sort, descending (key desc, idx asc via ~idx) ----
    for (int kk = 2; kk <= PADK; kk <<= 1) {
        for (int j = kk >> 1; j > 0; j >>= 1) {
            __syncthreads();
            #pragma unroll
            for (int half = 0; half < 2; ++half) {
                int i = t + half * 256;
                int ixj = i ^ j;
                if (ixj > i) {
                    ull a = sSel[i], c = sSel[ixj];
                    bool desc = ((i & kk) == 0);
                    bool sw = desc ? (a < c) : (a > c);
                    if (sw) { sSel[i] = c; sSel[ixj] = a; }
                }
            }
        }
    }
    __syncthreads();

    // ---- extract + gather detection data ----
    for (int i = t; i < KTOP; i += 256) {
        ull s = sSel[i];
        uint32_t a = 0xFFFFFFFFu - (uint32_t)(s & 0xFFFFFFFFull);
        const float* p = pred + ((size_t)b * NA + a) * 85;
        float x = p[0], y = p[1], w = p[2], h = p[3], obj = p[4];
        float best = p[5]; int bc = 0;
        for (int c = 1; c < NC; ++c) { float v = p[5 + c]; if (v > best) { best = v; bc = c; } }
        float hw = w * 0.5f, hh = h * 0.5f;
        sB0[i] = x - hw; sB1[i] = y - hh; sB2[i] = x + hw; sB3[i] = y + hh;
        sObj[i] = obj; sConf[i] = best; sCls[i] = bc;
    }
    __syncthreads();

    // ---- precompute suppression bitmasks: mask[i] bit j set iff j>i && iou>0.45 ----
    for (int item = t; item < KTOP * 5; item += 256) {
        int i = item / 5, w = item % 5;
        float x1 = sB0[i], y1 = sB1[i], x2 = sB2[i], y2 = sB3[i];
        float ai = fmaxf(x2 - x1, 0.0f) * fmaxf(y2 - y1, 0.0f);
        ull bits = 0ull;
        int j0 = w * 64;
        int jmax = j0 + 64; if (jmax > KTOP) jmax = KTOP;
        int jbeg = (j0 > i + 1) ? j0 : (i + 1);
        for (int j = jbeg; j < jmax; ++j) {
            float bx1 = sB0[j], by1 = sB1[j], bx2 = sB2[j], by2 = sB3[j];
            float aj = fmaxf(bx2 - bx1, 0.0f) * fmaxf(by2 - by1, 0.0f);
            float iw = fminf(x2, bx2) - fmaxf(x1, bx1); iw = fmaxf(iw, 0.0f);
            float ih = fminf(y2, by2) - fmaxf(y1, by1); ih = fmaxf(ih, 0.0f);
            float inter = iw * ih;
            float den = ai + aj;      // mirror reference op order exactly
            den = den - inter;
            den = den + 1e-9f;
            float iou = inter / den;
            if (iou > 0.45f) bits |= (1ull << (j - j0));
        }
        sMask[item] = bits;
    }
    __syncthreads();

    // ---- keep-init via ballot (words 0..3 from the 4 waves, word 4 from wave 0) ----
    {
        bool k1 = ((uint32_t)(sSel[t] >> 32)) > 0x007FFFFFu;   // i = t in [0,256)
        ull m1 = __ballot(k1);
        if ((t & 63) == 0) sKeepW[t >> 6] = m1;
        if (t < 64) {
            int i2 = 256 + t;                                   // pads have key 0 -> false
            bool k2 = ((uint32_t)(sSel[i2] >> 32)) > 0x007FFFFFu;
            ull m2 = __ballot(k2);
            if (t == 0) sKeepW[4] = m2 & ((1ull << 44) - 1);    // bits for i = 256..299
        }
    }
    __syncthreads();

    // ---- greedy NMS on wave 0: masks in registers, ctz skip between accepts ----
    if (t < 64) {
        ull rm[5][5];   // rm[w][ww] = suppression row for i = w*64 + lane, word ww
        #pragma unroll
        for (int w = 0; w < 5; ++w) {
            int i = w * 64 + t;
            #pragma unroll
            for (int ww = 0; ww < 5; ++ww)
                rm[w][ww] = (i < KTOP) ? sMask[i * 5 + ww] : 0ull;
        }
        ull kw[5];
        #pragma unroll
        for (int w = 0; w < 5; ++w) kw[w] = sKeepW[w];   // replicated in every lane

        #pragma unroll
        for (int w = 0; w < 5; ++w) {
            ull cur = kw[w];
            while (cur) {
                int ib = __builtin_ctzll(cur);           // accepted box i = w*64+ib
                ull m0 = __shfl(rm[w][0], ib);
                ull m1 = __shfl(rm[w][1], ib);
                ull m2 = __shfl(rm[w][2], ib);
                ull m3 = __shfl(rm[w][3], ib);
                ull m4 = __shfl(rm[w][4], ib);
                kw[0] &= ~m0; kw[1] &= ~m1; kw[2] &= ~m2; kw[3] &= ~m3; kw[4] &= ~m4;
                ull done = (ib == 63) ? 0ull : (~0ull << (ib + 1));
                cur = kw[w] & done;                      // next surviving candidate in word
            }
        }
        if (t == 0) {
            #pragma unroll
            for (int w = 0; w < 5; ++w) sKeepW[w] = kw[w];
        }
    }
    __syncthreads();

    // ---- outputs (all float32, concatenated in return order) ----
    // boxes_yxyx (32,300,4) @0 ; in_zone @38400 ; scores @48000 ; classes @57600 ;
    // centers_yx (32,300,2) @67200 ; keep @86400 ; total 96000
    const size_t o1 = 38400, o2 = 48000, o3 = 57600, o4 = 67200, o5 = 86400;
    const size_t bo = (size_t)b * KTOP;
    for (int i = t; i < KTOP; i += 256) {
        int kp = (int)((sKeepW[i >> 6] >> (i & 63)) & 1ull);
        float x1 = sB0[i], y1 = sB1[i], x2 = sB2[i], y2 = sB3[i];
        out[(bo + i) * 4 + 0] = y1;
        out[(bo + i) * 4 + 1] = x1;
        out[(bo + i) * 4 + 2] = y2;
        out[(bo + i) * 4 + 3] = x2;
        float cx = (x1 + x2) * 0.5f;
        float cy = (y1 + y2) * 0.5f;
        int cnt = 0;
        #pragma unroll
        for (int e = 0; e < 8; ++e) {
            float xi = sZone[2 * e], yi = sZone[2 * e + 1];
            int ep = (e + 7) & 7;               // zr = roll(zone, 1): partner is zone[e-1]
            float xj = sZone[2 * ep], yj = sZone[2 * ep + 1];
            bool gyi = yi > cy, gyj = yj > cy;
            if (gyi != gyj) {
                float gx = (xj - xi) * (cy - yi) / (yj - yi) + xi;
                if (gx > cx) cnt++;
            }
        }
        int inz = (((cnt & 1) != 0) && kp) ? 1 : 0;
        out[o1 + bo + i] = (float)inz;
        out[o2 + bo + i] = fmaxf(sObj[i], sConf[i]);
        out[o3 + bo + i] = (float)sCls[i];
        out[o4 + (bo + i) * 2 + 0] = cy;
        out[o4 + (bo + i) * 2 + 1] = cx;
        out[o5 + bo + i] = (float)kp;
    }
}

extern "C" void kernel_launch(void* const* d_in, const int* in_sizes, int n_in,
                              void* d_out, int out_size, void* d_ws, size_t ws_size,
                              hipStream_t stream) {
    const float* pred = (const float*)d_in[0];   // (32,8400,85) fp32
    const float* zone = (const float*)d_in[1];   // (8,2) fp32
    float* out = (float*)d_out;                  // 96000 fp32
    uint32_t* keys = (uint32_t*)d_ws;            // 268800 * 4 B scratch

    score_kernel<<<(NB * NA) / 128, 256, 0, stream>>>(pred, keys);
    nms_kernel<<<NB, 256, 0, stream>>>(pred, zone, keys, out);
}

// Round 3
// 204.174 us; speedup vs baseline: 1.5293x; 1.1953x over previous
//
#include <hip/hip_runtime.h>
#include <stdint.h>

typedef unsigned long long ull;

#define NA 8400
#define NB 32
#define KTOP 300
#define NC 80
#define CH 33          // 256*33 = 8448 >= 8400
#define WS_STRIDE 33600  // bytes per batch region in ws (= 8400*4, the keys footprint)
#define OFF_SEL   0      // ull[300]  sorted (key<<32)|(~anchor)   (aliases keys, written after load)
#define OFF_KEEP  2400   // ull[5]    keep-init bit words
#define OFF_MASK  2560   // ull[1500] suppression masks [i][w]

// out layout: boxes_yxyx @0 ; in_zone @38400 ; scores @48000 ; classes @57600 ;
//             centers_yx @67200 ; keep @86400 ; total 96000 floats
#define O1 38400
#define O2 48000
#define O3 57600
#define O4 67200
#define O5 86400

// ---------------- A: per-anchor score key ----------------
__global__ __launch_bounds__(256) void score_kernel(const float* __restrict__ pred,
                                                    uint32_t* __restrict__ keys) {
    __shared__ float sP[128 * 85];
    const int blk = blockIdx.x;                       // 2100 blocks * 128 anchors
    const float4* g4 = (const float4*)(pred + (size_t)blk * 128 * 85);
    float4* l4 = (float4*)sP;
    for (int i = threadIdx.x; i < (128 * 85 / 4); i += 256) l4[i] = g4[i];
    __syncthreads();
    const int t = threadIdx.x;
    if (t < 128) {
        const float* p = sP + t * 85;
        float obj = p[4];
        // 4-way interleaved max to break the 80-deep dependence chain (no NaN in inputs)
        float b0 = p[5], b1 = p[6], b2 = p[7], b3 = p[8];
        #pragma unroll
        for (int c = 4; c < NC; c += 4) {
            b0 = fmaxf(b0, p[5 + c]);
            b1 = fmaxf(b1, p[6 + c]);
            b2 = fmaxf(b2, p[7 + c]);
            b3 = fmaxf(b3, p[8 + c]);
        }
        float best = fmaxf(fmaxf(b0, b1), fmaxf(b2, b3));
        float sc = obj * best;
        uint32_t u = (sc >= 0.2f) ? (__float_as_uint(sc) | 0x80000000u) : 0x007FFFFFu;
        keys[(size_t)blk * 128 + t] = u;
    }
}

// ---------------- B: per-batch exact top-300 (radix select + rank sort) ----------------
__global__ __launch_bounds__(256) void select_kernel(const uint32_t* keys, uint8_t* ws) {
    __shared__ uint32_t sKeys[8448];
    __shared__ ull sSel[KTOP];
    __shared__ ull sSorted[KTOP];
    __shared__ uint32_t sH4[1024];
    __shared__ uint32_t sScanA[256];
    __shared__ uint32_t sScanB[256];
    __shared__ uint32_t sBc[2];
    __shared__ int sCnt;

    const int b = blockIdx.x;
    const int t = threadIdx.x;
    const int wv = t >> 6;

    for (int e = t; e < NA; e += 256) sKeys[e] = keys[(size_t)b * NA + e];
    for (int e = NA + t; e < 8448; e += 256) sKeys[e] = 0u;
    if (t == 0) sCnt = 0;
    __syncthreads();

    // ---- radix select: exact 300th-largest key ----
    uint32_t prefix = 0, r = KTOP;
    const int beg = t * CH;
    const int end = (beg + CH < NA) ? beg + CH : NA;
    for (int round = 0; round < 4; ++round) {
        const int shift = 24 - 8 * round;
        for (int idx = t; idx < 1024; idx += 256) sH4[idx] = 0u;
        __syncthreads();
        const uint32_t pmask = (round == 0) ? 0u : (0xFFFFFFFFu << (shift + 8));
        for (int e = beg; e < end; ++e) {
            uint32_t k = sKeys[e];
            if ((k & pmask) == (prefix & pmask))
                atomicAdd(&sH4[(wv << 8) + ((k >> shift) & 0xFFu)], 1u);
        }
        __syncthreads();
        sScanA[t] = sH4[t] + sH4[256 + t] + sH4[512 + t] + sH4[768 + t];
        __syncthreads();
        uint32_t* src = sScanA;
        uint32_t* dst = sScanB;
        for (int off = 1; off < 256; off <<= 1) {        // inclusive suffix scan
            uint32_t v = src[t];
            if (t + off < 256) v += src[t + off];
            dst[t] = v;
            __syncthreads();
            uint32_t* tmp = src; src = dst; dst = tmp;
        }
        uint32_t S = src[t];
        uint32_t above = (t < 255) ? src[t + 1] : 0;
        if (above < r && S >= r) {
            sBc[0] = prefix | ((uint32_t)t << shift);
            sBc[1] = r - above;
        }
        __syncthreads();
        prefix = sBc[0]; r = sBc[1];
        __syncthreads();
    }
    const uint32_t kth = prefix;
    const uint32_t rem = r;
    const uint32_t cntgt = KTOP - rem;

    // ---- compact the top-300 set into sSel (unordered) ----
    {
        uint32_t eqc = 0;
        for (int e = beg; e < end; ++e) {
            uint32_t k = sKeys[e];
            if (k > kth) {
                int p = atomicAdd(&sCnt, 1);
                sSel[p] = ((ull)k << 32) | (ull)(0xFFFFFFFFu - (uint32_t)e);
            } else if (k == kth) eqc++;
        }
        sScanA[t] = eqc;
        __syncthreads();
        uint32_t* src = sScanA;
        uint32_t* dst = sScanB;
        for (int off = 1; off < 256; off <<= 1) {        // inclusive prefix scan
            uint32_t v = src[t];
            if (t >= off) v += src[t - off];
            dst[t] = v;
            __syncthreads();
            uint32_t* tmp = src; src = dst; dst = tmp;
        }
        uint32_t off0 = (t > 0) ? src[t - 1] : 0;
        for (int e = beg; e < end; ++e) {
            uint32_t k = sKeys[e];
            if (k == kth) {
                if (off0 < rem)
                    sSel[cntgt + off0] = ((ull)k << 32) | (ull)(0xFFFFFFFFu - (uint32_t)e);
                off0++;
            }
        }
        __syncthreads();
    }

    // ---- rank sort: 64-bit entries are unique -> ranks are a permutation ----
    ull my0 = sSel[t];
    ull my1 = (t < KTOP - 256) ? sSel[256 + t] : 0ull;
    int r0 = 0, r1 = 0;
    for (int j = 0; j < KTOP; ++j) {
        ull v = sSel[j];                 // broadcast read
        r0 += (v > my0) ? 1 : 0;
        r1 += (v > my1) ? 1 : 0;
    }
    sSorted[r0] = my0;
    if (t < KTOP - 256) sSorted[r1] = my1;
    __syncthreads();

    // ---- keep-init ballots + store sorted selection (keys region now dead) ----
    ull* selW = (ull*)(ws + (size_t)b * WS_STRIDE + OFF_SEL);
    ull* keepW = (ull*)(ws + (size_t)b * WS_STRIDE + OFF_KEEP);
    bool f = ((uint32_t)(sSorted[t] >> 32)) > 0x007FFFFFu;
    ull m = __ballot(f);
    if ((t & 63) == 0) keepW[t >> 6] = m;
    if (t < 64) {
        bool f2 = (t < KTOP - 256) && (((uint32_t)(sSorted[256 + t] >> 32)) > 0x007FFFFFu);
        ull m2 = __ballot(f2);
        if (t == 0) keepW[4] = m2;
    }
    selW[t] = sSorted[t];
    if (t < KTOP - 256) selW[256 + t] = sSorted[256 + t];
}

// ---------------- C: gather + IoU masks + keep-independent outputs ----------------
// grid (6, 32): role 0..4 -> mask word, role 5 -> detail gather + outputs
__global__ __launch_bounds__(256) void prep_kernel(const float* __restrict__ pred,
                                                   uint8_t* ws,
                                                   float* __restrict__ out) {
    #pragma clang fp contract(off)
    __shared__ float sB0[KTOP], sB1[KTOP], sB2[KTOP], sB3[KTOP];
    const int role = blockIdx.x;
    const int b = blockIdx.y;
    const int t = threadIdx.x;
    const ull* sel = (const ull*)(ws + (size_t)b * WS_STRIDE + OFF_SEL);

    if (role < 5) {
        for (int i = t; i < KTOP; i += 256) {
            uint32_t a = 0xFFFFFFFFu - (uint32_t)sel[i];
            const float* p = pred + ((size_t)b * NA + a) * 85;
            float x = p[0], y = p[1], w = p[2], h = p[3];
            float hw = w * 0.5f, hh = h * 0.5f;
            sB0[i] = x - hw; sB1[i] = y - hh; sB2[i] = x + hw; sB3[i] = y + hh;
        }
        __syncthreads();
        ull* mask = (ull*)(ws + (size_t)b * WS_STRIDE + OFF_MASK);
        const int j0 = role * 64;
        int jmax = j0 + 64; if (jmax > KTOP) jmax = KTOP;
        for (int i = t; i < KTOP; i += 256) {
            float x1 = sB0[i], y1 = sB1[i], x2 = sB2[i], y2 = sB3[i];
            float ai = fmaxf(x2 - x1, 0.0f) * fmaxf(y2 - y1, 0.0f);
            ull bits = 0ull;
            int jbeg = (j0 > i + 1) ? j0 : (i + 1);
            for (int j = jbeg; j < jmax; ++j) {
                float bx1 = sB0[j], by1 = sB1[j], bx2 = sB2[j], by2 = sB3[j];
                float aj = fmaxf(bx2 - bx1, 0.0f) * fmaxf(by2 - by1, 0.0f);
                float iw = fminf(x2, bx2) - fmaxf(x1, bx1); iw = fmaxf(iw, 0.0f);
                float ih = fminf(y2, by2) - fmaxf(y1, by1); ih = fmaxf(ih, 0.0f);
                float inter = iw * ih;
                float den = ai + aj;          // mirror reference op order exactly
                den = den - inter;
                den = den + 1e-9f;
                float iou = inter / den;
                if (iou > 0.45f) bits |= (1ull << (j - j0));
            }
            mask[i * 5 + role] = bits;
        }
    } else {
        const size_t bo = (size_t)b * KTOP;
        for (int i = t; i < KTOP; i += 256) {
            uint32_t a = 0xFFFFFFFFu - (uint32_t)sel[i];
            const float* p = pred + ((size_t)b * NA + a) * 85;
            float x = p[0], y = p[1], w = p[2], h = p[3], obj = p[4];
            float best = p[5]; int bc = 0;
            for (int c = 1; c < NC; ++c) {     // sequential: argmax must keep FIRST max
                float v = p[5 + c];
                if (v > best) { best = v; bc = c; }
            }
            float hw = w * 0.5f, hh = h * 0.5f;
            float x1 = x - hw, y1 = y - hh, x2 = x + hw, y2 = y + hh;
            out[(bo + i) * 4 + 0] = y1;
            out[(bo + i) * 4 + 1] = x1;
            out[(bo + i) * 4 + 2] = y2;
            out[(bo + i) * 4 + 3] = x2;
            out[O4 + (bo + i) * 2 + 0] = (y1 + y2) * 0.5f;
            out[O4 + (bo + i) * 2 + 1] = (x1 + x2) * 0.5f;
            out[O2 + bo + i] = fmaxf(obj, best);
            out[O3 + bo + i] = (float)bc;
        }
    }
}

// ---------------- D: greedy NMS + keep/in_zone outputs (1 wave per batch) ----------------
__global__ __launch_bounds__(64) void finish_kernel(const float* __restrict__ zone,
                                                    const uint8_t* ws,
                                                    float* __restrict__ out) {
    #pragma clang fp contract(off)
    __shared__ float sZone[16];
    const int b = blockIdx.x;
    const int L = threadIdx.x;
    const ull* mask = (const ull*)(ws + (size_t)b * WS_STRIDE + OFF_MASK);
    const ull* keepI = (const ull*)(ws + (size_t)b * WS_STRIDE + OFF_KEEP);
    if (L < 16) sZone[L] = zone[L];

    ull rm[5][5];
    #pragma unroll
    for (int w = 0; w < 5; ++w) {
        int i = w * 64 + L;
        #pragma unroll
        for (int ww = 0; ww < 5; ++ww)
            rm[w][ww] = (i < KTOP) ? mask[i * 5 + ww] : 0ull;
    }
    ull kw[5];
    #pragma unroll
    for (int w = 0; w < 5; ++w) kw[w] = keepI[w];   // replicated in every lane
    __syncthreads();                                 // sZone ready

    #pragma unroll
    for (int w = 0; w < 5; ++w) {
        ull cur = kw[w];
        while (cur) {
            int ib = __builtin_ctzll(cur);          // accepted box i = w*64+ib
            ull m0 = __shfl(rm[w][0], ib);
            ull m1 = __shfl(rm[w][1], ib);
            ull m2 = __shfl(rm[w][2], ib);
            ull m3 = __shfl(rm[w][3], ib);
            ull m4 = __shfl(rm[w][4], ib);
            kw[0] &= ~m0; kw[1] &= ~m1; kw[2] &= ~m2; kw[3] &= ~m3; kw[4] &= ~m4;
            ull done = (ib == 63) ? 0ull : (~0ull << (ib + 1));
            cur = kw[w] & done;
        }
    }

    const size_t bo = (size_t)b * KTOP;
    #pragma unroll
    for (int h = 0; h < 5; ++h) {
        int i = h * 64 + L;
        if (i < KTOP) {
            int kp = (int)((kw[h] >> L) & 1ull);
            float cy = out[O4 + (bo + i) * 2 + 0];
            float cx = out[O4 + (bo + i) * 2 + 1];
            int cnt = 0;
            #pragma unroll
            for (int e = 0; e < 8; ++e) {
                float xi = sZone[2 * e], yi = sZone[2 * e + 1];
                int ep = (e + 7) & 7;               // zr = roll(zone, 1)
                float xj = sZone[2 * ep], yj = sZone[2 * ep + 1];
                bool gyi = yi > cy, gyj = yj > cy;
                if (gyi != gyj) {
                    float gx = (xj - xi) * (cy - yi) / (yj - yi) + xi;
                    if (gx > cx) cnt++;
                }
            }
            int inz = (((cnt & 1) != 0) && kp) ? 1 : 0;
            out[O1 + bo + i] = (float)inz;
            out[O5 + bo + i] = (float)kp;
        }
    }
}

extern "C" void kernel_launch(void* const* d_in, const int* in_sizes, int n_in,
                              void* d_out, int out_size, void* d_ws, size_t ws_size,
                              hipStream_t stream) {
    const float* pred = (const float*)d_in[0];   // (32,8400,85) fp32
    const float* zone = (const float*)d_in[1];   // (8,2) fp32
    float* out = (float*)d_out;                  // 96000 fp32
    uint32_t* keys = (uint32_t*)d_ws;            // per-batch regions, 33600 B each
    uint8_t* ws = (uint8_t*)d_ws;

    score_kernel<<<(NB * NA) / 128, 256, 0, stream>>>(pred, keys);
    select_kernel<<<NB, 256, 0, stream>>>(keys, ws);
    prep_kernel<<<dim3(6, NB), 256, 0, stream>>>(pred, ws, out);
    finish_kernel<<<NB, 64, 0, stream>>>(zone, ws, out);
}